// Round 1
// 77.495 us; speedup vs baseline: 1.0121x; 1.0121x over previous
//
#include <hip/hip_runtime.h>
#include <hip/hip_bf16.h>

// Problem: VectorQuantizer, B=8 C=16 H=64 W=64, D=1, N=512.
// E = 524288 input/output elements + 2 scalar losses.
//
// Reference semantics (including the deliberate reshape bug):
//   argmin_flat[i] over n of (x_flat[i] - weight[n])^2, i in BCHW order
//   quantized[b,c,h,w] = weight[ argmin_flat[ ((b*H+h)*W+w)*C + c ] ]
//   both losses = mean over BCHW of (x - quantized)^2
//
// R4: sorted-codebook predecessor search, exact fp32 sub-then-square
//     neighbor compare. absmax=0 verified.
// R6 lesson: 2048+ same-address device atomics serialize -> +45us.
// R8 lesson: per-block __threadfence (device scope, cross-XCD L2
//     writeback) costs ~17us across 1024 blocks.
// R9: measured-best structure: 3 dispatches, plain-store per-block
//     partials, no device fences, no atomics.
// R10 (this round): rocprof top-5 shows the harness's 256 MiB ws poison
//     fill (~41us @ 82% HBM peak) dominating; our kernels are below the
//     cutoff. Remaining kernel-side lever is per-element overhead:
//     M=2 -> 4 (512 blocks: halves staging loads, barriers, partials;
//     float4 load/store), reduce kernel to a single wave (no LDS/barrier).
//     Search concurrency unchanged: 2 waves/SIMD x 4 chains = 8.

#define E_TOTAL 524288
#define NCODE   512
#define BLOCK   256
#define M       4
#define NBLOCKS_M (E_TOTAL / (BLOCK * M))   // 512 blocks, 2 blocks/CU

#define SKEW(a) ((a) + ((a) >> 5))          // LDS anti-conflict skew

// ---- prep: rank-sort the 512 codes ascending into ws ----
__global__ __launch_bounds__(64) void vq_prep_kernel(
    const float* __restrict__ wt, float* __restrict__ sorted) {
  __shared__ float4 lw4[NCODE / 4];   // 2 KB
  const int t = threadIdx.x;
  lw4[t] = ((const float4*)wt)[t];
  lw4[t + 64] = ((const float4*)wt)[t + 64];
  __syncthreads();

  const int i = blockIdx.x * 64 + t;        // code index this thread ranks
  const float v = ((const float*)lw4)[i];
  int r = 0;
#pragma unroll 8
  for (int j = 0; j < NCODE / 4; ++j) {
    const float4 u = lw4[j];                // wave-uniform ds_read_b128
    const int n0 = 4 * j;
    r += (u.x < v || (u.x == v && (n0 + 0) < i)) ? 1 : 0;  // stable rank
    r += (u.y < v || (u.y == v && (n0 + 1) < i)) ? 1 : 0;  // (dup-safe)
    r += (u.z < v || (u.z == v && (n0 + 2) < i)) ? 1 : 0;
    r += (u.w < v || (u.w == v && (n0 + 3) < i)) ? 1 : 0;
  }
  sorted[r] = v;
}

// ---- main: binary search + neighbor compare + loss partials ----
__global__ __launch_bounds__(BLOCK) void vq_main_kernel(
    const float* __restrict__ x, const float* __restrict__ sorted,
    float* __restrict__ out, double* __restrict__ partial) {
  __shared__ float ls[SKEW(NCODE + 1) + 1];  // skewed; logical 0..512
  __shared__ double lsum[BLOCK / 64];

  const int t = threadIdx.x;
  const int tid = blockIdx.x * BLOCK + t;
  const int o0 = tid * M;               // four consecutive outputs, BCHW flat
  // Decode o0 -> (b,c,h,w): W=64 (6b), H=64 (6b), C=16 (4b), B=8 (3b).
  // o0 % 4 == 0 => w % 4 == 0 => o0..o0+3 share b,c,h; ip step = +16.
  const int w = o0 & 63;
  const int h = (o0 >> 6) & 63;
  const int c = (o0 >> 12) & 15;
  const int b = o0 >> 16;
  // Scrambled source index (the reference's reshape-as-[B,H,W,C] bug):
  const int ip0 = b * 65536 + h * 1024 + w * 16 + c;

  // Issue gathers + coalesced loss-load early; latency overlaps staging.
  const float g0 = x[ip0];
  const float g1 = x[ip0 + 16];
  const float g2 = x[ip0 + 32];
  const float g3 = x[ip0 + 48];
  const float4 xo = ((const float4*)x)[tid];

  // Stage sorted codebook, skewed: logical a -> physical a+(a>>5).
  // 256 threads x float2 = all 512 codes in one pass.
  const float2 s2 = ((const float2*)sorted)[t];
  ls[SKEW(2 * t + 1)] = s2.x;
  ls[SKEW(2 * t + 2)] = s2.y;
  if (t == 0) ls[SKEW(0)] = -3.0e38f;   // left sentinel (logical 0)
  __syncthreads();

  // Branchless lower-bound over 512: idx = min(#{sorted <= x}, 511).
  unsigned i0 = 0, i1 = 0, i2 = 0, i3 = 0;
#pragma unroll
  for (unsigned step = NCODE / 2; step; step >>= 1) {
    const float s0 = ls[SKEW(i0 + step)];
    const float s1 = ls[SKEW(i1 + step)];
    const float s2v = ls[SKEW(i2 + step)];
    const float s3 = ls[SKEW(i3 + step)];
    i0 = (s0 <= g0) ? i0 + step : i0;   // predicated (v_cndmask)
    i1 = (s1 <= g1) ? i1 + step : i1;
    i2 = (s2v <= g2) ? i2 + step : i2;
    i3 = (s3 <= g3) ? i3 + step : i3;
  }
  const float l0 = ls[SKEW(i0)], r0 = ls[SKEW(i0 + 1)];
  const float l1 = ls[SKEW(i1)], r1 = ls[SKEW(i1 + 1)];
  const float l2 = ls[SKEW(i2)], r2 = ls[SKEW(i2 + 1)];
  const float l3 = ls[SKEW(i3)], r3 = ls[SKEW(i3 + 1)];
  // Exact reference arithmetic: fp32 subtract then square.
  const float dl0 = g0 - l0, dr0 = g0 - r0;
  const float dl1 = g1 - l1, dr1 = g1 - r1;
  const float dl2 = g2 - l2, dr2 = g2 - r2;
  const float dl3 = g3 - l3, dr3 = g3 - r3;
  const float wq0 = (dl0 * dl0 <= dr0 * dr0) ? l0 : r0;
  const float wq1 = (dl1 * dl1 <= dr1 * dr1) ? l1 : r1;
  const float wq2 = (dl2 * dl2 <= dr2 * dr2) ? l2 : r2;
  const float wq3 = (dl3 * dl3 <= dr3 * dr3) ? l3 : r3;

  ((float4*)out)[tid] = make_float4(wq0, wq1, wq2, wq3);

  const float d0 = xo.x - wq0;
  const float d1 = xo.y - wq1;
  const float d2 = xo.z - wq2;
  const float d3 = xo.w - wq3;
  double ds = (double)d0 * (double)d0 + (double)d1 * (double)d1 +
              (double)d2 * (double)d2 + (double)d3 * (double)d3;

  // Wave(64) shuffle reduction, then per-block partial (plain store).
#pragma unroll
  for (int off = 32; off > 0; off >>= 1) ds += __shfl_down(ds, off, 64);
  const int lane = t & 63, wave = t >> 6;
  if (lane == 0) lsum[wave] = ds;
  __syncthreads();
  if (t == 0) {
    double s = 0.0;
#pragma unroll
    for (int i = 0; i < BLOCK / 64; ++i) s += lsum[i];
    partial[blockIdx.x] = s;  // full overwrite: no ws zeroing needed
  }
}

// Single wave: 512 doubles = 8 loads/lane, shuffle reduce, no LDS/barrier.
__global__ __launch_bounds__(64) void vq_reduce_kernel(
    const double* __restrict__ partial, float* __restrict__ out) {
  const int t = threadIdx.x;
  double s = 0.0;
#pragma unroll
  for (int k = 0; k < NBLOCKS_M / 64; ++k) s += partial[t + 64 * k];
#pragma unroll
  for (int off = 32; off > 0; off >>= 1) s += __shfl_down(s, off, 64);
  if (t == 0) {
    const float m = (float)(s / (double)E_TOTAL);
    out[E_TOTAL] = m;      // q_latent_loss
    out[E_TOTAL + 1] = m;  // e_latent_loss (identical forward value)
  }
}

extern "C" void kernel_launch(void* const* d_in, const int* in_sizes, int n_in,
                              void* d_out, int out_size, void* d_ws, size_t ws_size,
                              hipStream_t stream) {
  const float* x = (const float*)d_in[0];    // 524288 fp32, BCHW flat
  const float* wt = (const float*)d_in[1];   // 512 fp32 (D=1 row)
  float* out = (float*)d_out;                // 524290 fp32
  float* sorted = (float*)d_ws;              // 512 fp32 (2048 B)
  double* partial = (double*)((char*)d_ws + 4096);  // 512 doubles

  vq_prep_kernel<<<8, 64, 0, stream>>>(wt, sorted);
  vq_main_kernel<<<NBLOCKS_M, BLOCK, 0, stream>>>(x, sorted, out, partial);
  vq_reduce_kernel<<<1, 64, 0, stream>>>(partial, out);
}